// Round 12
// baseline (912.125 us; speedup 1.0000x reference)
//
#include <hip/hip_runtime.h>

// ---------------------------------------------------------------------------
// MoE forward (top-2 of 8 experts), sparse-routed, bf16 MFMA.
// Round 12 = Round 11 with gemm1 split into 4 dispatches (2 experts each),
//   PURELY for rocprof visibility: top-5 slots were saturated by gemm1
//   replays, hiding the true #2 kernel. Everything else byte-identical.
// ---------------------------------------------------------------------------

typedef __bf16 bf16x8 __attribute__((ext_vector_type(8)));
typedef float f32x4 __attribute__((ext_vector_type(4)));
typedef unsigned short us8 __attribute__((ext_vector_type(8)));

#define T_TOK 8192
#define DIMD 1024
#define NEXP 8
#define HID 2730
#define HPAD 2752
#define H2PAD 5504
#define NPAIR 16384

#define WS_CTRL  ((size_t)0)
#define WS_TOPI  ((size_t)256)
#define WS_TOPW  (WS_TOPI + 65536)
#define WS_PW    (WS_TOPW + 65536)
#define WS_PTOK  (WS_PW + 65536)
#define WS_XB    (WS_PTOK + 65536)
#define WS_W12T  (WS_XB + (size_t)16777216)
#define WS_W3T   (WS_W12T + (size_t)90177536)
#define WS_HBUF  (WS_W3T + (size_t)45088768)

#define GLOAD16(g, l) __builtin_amdgcn_global_load_lds( \
    (const __attribute__((address_space(1))) void*)(g), \
    (__attribute__((address_space(3))) void*)(l), 16, 0, 0)

__device__ __forceinline__ unsigned short f2bf(float f) {
    unsigned int u = __float_as_uint(f);
    u += 0x7fffu + ((u >> 16) & 1u);
    return (unsigned short)(u >> 16);
}

// ---------------- W12 -> bf16, transposed [e][half][jp(2752)][k(1024)] ------
__global__ void k_cvt_w12t(const float* __restrict__ w12, unsigned short* __restrict__ w12t) {
    int jt = blockIdx.x;              // 0..171
    int kt = blockIdx.y;              // 0..7
    int e  = blockIdx.z;
    int half = jt / 86, jt2 = jt % 86;
    int jh0 = jt2 * 32, k0 = kt * 128;
    __shared__ float tile[32][133];   // [j][k]
    int t = threadIdx.x;
    {
        int lane_j = t & 15, krow = t >> 4;
#pragma unroll
        for (int p = 0; p < 8; ++p) {
            int kk = p * 16 + krow;
            int j = jh0 + lane_j * 2;
            float2 v = make_float2(0.f, 0.f);
            if (j < HID)
                v = *(const float2*)(w12 + (size_t)(e * 1024 + k0 + kk) * 5460 + half * HID + j);
            tile[lane_j * 2][kk] = v.x;
            tile[lane_j * 2 + 1][kk] = v.y;
        }
    }
    __syncthreads();
    {
        int jj = t >> 3, kc = t & 7;
        unsigned short* dst = w12t + ((size_t)e * H2PAD + half * HPAD + jh0 + jj) * 1024 + k0;
#pragma unroll
        for (int cc = 0; cc < 2; ++cc) {
            int c = kc + cc * 8;
            us8 v;
#pragma unroll
            for (int b = 0; b < 8; ++b) v[b] = f2bf(tile[jj][c * 8 + b]);
            *(us8*)(dst + c * 8) = v;
        }
    }
}

// ---------------- W3 -> bf16, transposed [e][d(1024)][k(2752)] --------------
__global__ void k_cvt_w3t(const float* __restrict__ w3, unsigned short* __restrict__ w3t) {
    int kt = blockIdx.x;              // 0..21
    int dt = blockIdx.y;              // 0..31
    int e  = blockIdx.z;
    int k0 = kt * 128, d0 = dt * 32;
    __shared__ float tile[32][133];   // [d][k]
    int t = threadIdx.x;
    {
        int lane_d = t & 15, krow = t >> 4;
#pragma unroll
        for (int p = 0; p < 8; ++p) {
            int kk = k0 + p * 16 + krow;
            float2 v = make_float2(0.f, 0.f);
            if (kk < HID)
                v = *(const float2*)(w3 + (size_t)(e * HID + kk) * 1024 + d0 + lane_d * 2);
            tile[lane_d * 2][p * 16 + krow] = v.x;
            tile[lane_d * 2 + 1][p * 16 + krow] = v.y;
        }
    }
    __syncthreads();
    {
        int dd = t >> 3, kc = t & 7;
        unsigned short* dst = w3t + ((size_t)e * 1024 + d0 + dd) * HPAD + k0;
#pragma unroll
        for (int cc = 0; cc < 2; ++cc) {
            int c = kc + cc * 8;
            if (k0 + c * 8 < HPAD) {
                us8 v;
#pragma unroll
                for (int b = 0; b < 8; ++b) v[b] = f2bf(tile[dd][c * 8 + b]);
                *(us8*)(dst + c * 8) = v;
            }
        }
    }
}

// ---------------- router (fused x->bf16): fp64 logits, stable top-2 ---------
__global__ void k_router(const float4* __restrict__ x4, const float* __restrict__ wr,
                         ushort4* __restrict__ xb4,
                         int* __restrict__ topi, float* __restrict__ topw,
                         int* __restrict__ ctrl) {
    int wid = threadIdx.x >> 6, lane = threadIdx.x & 63;
    int t = blockIdx.x * 4 + wid;
    const float4* xr = x4 + (size_t)t * 256;
    double acc[NEXP];
#pragma unroll
    for (int e = 0; e < NEXP; ++e) acc[e] = 0.0;
#pragma unroll
    for (int it = 0; it < 4; ++it) {
        int d4 = it * 64 + lane;
        float4 v = xr[d4];
        ushort4 r;
        r.x = f2bf(v.x); r.y = f2bf(v.y); r.z = f2bf(v.z); r.w = f2bf(v.w);
        xb4[(size_t)t * 256 + d4] = r;
        const float* w = wr + (size_t)d4 * 4 * NEXP;
#pragma unroll
        for (int e = 0; e < NEXP; ++e) {
            acc[e] += (double)v.x * (double)w[e]
                    + (double)v.y * (double)w[NEXP + e]
                    + (double)v.z * (double)w[2 * NEXP + e]
                    + (double)v.w * (double)w[3 * NEXP + e];
        }
    }
#pragma unroll
    for (int e = 0; e < NEXP; ++e) {
        for (int off = 32; off > 0; off >>= 1) acc[e] += __shfl_down(acc[e], off);
    }
    if (lane == 0) {
        double b0 = -1e300, b1 = -1e300; int i0 = 0, i1 = 0;
#pragma unroll
        for (int e = 0; e < NEXP; ++e) {
            double v = acc[e];
            if (v > b0) { b1 = b0; i1 = i0; b0 = v; i0 = e; }
            else if (v > b1) { b1 = v; i1 = e; }
        }
        float e1 = expf((float)(b1 - b0));
        float w0 = 1.0f / (1.0f + e1);
        float w1 = e1 / (1.0f + e1);
        topi[2 * t] = i0; topi[2 * t + 1] = i1;
        topw[2 * t] = w0; topw[2 * t + 1] = w1;
        atomicAdd(&ctrl[i0], 1);
        atomicAdd(&ctrl[i1], 1);
    }
}

__global__ void k_scan(int* ctrl) {
    if (threadIdx.x == 0 && blockIdx.x == 0) {
        int s = 0;
        for (int e = 0; e < NEXP; ++e) { ctrl[16 + e] = s; s += ctrl[e]; }
        ctrl[16 + NEXP] = s;
    }
}

__global__ void k_compact(const int* __restrict__ topi, const float* __restrict__ topw,
                          int* __restrict__ ctrl,
                          int* __restrict__ ptok, float* __restrict__ pw) {
    int t = blockIdx.x * 256 + threadIdx.x;
    if (t >= T_TOK) return;
#pragma unroll
    for (int k = 0; k < 2; ++k) {
        int e = topi[2 * t + k];
        int p = ctrl[16 + e] + atomicAdd(&ctrl[8 + e], 1);
        ptok[p] = t;
        pw[p] = topw[2 * t + k];
    }
}

// ---------------- GEMM1 + GLU: h = silu(x@W1)*(x@W2), bf16 out --------------
// BM=256 x BN=128(64j x 2 halves), BK=32, 512 thr, 8 waves (4M x 2N).
// Tri-buffered LDS 72KB (2 blocks/CU), 1 barrier/K-step, vmcnt(3).
// z-split into 4 launches (ebase param) for rocprof visibility.
__global__ __launch_bounds__(512, 4) void k_gemm1(
    const unsigned short* __restrict__ xb,
    const unsigned short* __restrict__ w12t,
    const int* __restrict__ ctrl,
    const int* __restrict__ ptok,
    unsigned short* __restrict__ hbuf,
    int ebase) {
    int e = ebase + blockIdx.z;
    int n_e = ctrl[e];
    int r0 = blockIdx.y * 256;
    if (r0 >= n_e) return;
    int p0 = ctrl[16 + e] + r0;
    int j0 = blockIdx.x * 64;

    __shared__ unsigned short AL[3][256][32];   // 48 KB
    __shared__ unsigned short BL[3][128][32];   // 24 KB

    int tid = threadIdx.x, lane = tid & 63, wid = tid >> 6;
    int wm = wid >> 1, wn = wid & 1;            // 4M x 2N
    int lr = lane & 15, lk = lane >> 4;

    unsigned short* ALp = &AL[0][0][0];
    unsigned short* BLp = &BL[0][0][0];

    int swzB = (((tid & 3) ^ ((tid >> 3) & 3)) << 4);
    const char* aSrc[2];
#pragma unroll
    for (int i = 0; i < 2; ++i) {
        int row = i * 128 + (tid >> 2);
        int tok = (r0 + row < n_e) ? ptok[p0 + row] : ptok[p0];
        aSrc[i] = (const char*)(xb + (size_t)tok * 1024) + swzB;
    }
    const char* bSrc;
    {
        int r = tid >> 2;                       // 0..127: half*64 + jj
        int half = r >> 6, jj = r & 63;
        bSrc = (const char*)(w12t + ((size_t)e * H2PAD + half * HPAD + j0 + jj) * 1024) + swzB;
    }

    f32x4 acc[4][2][2];
#pragma unroll
    for (int m = 0; m < 4; ++m)
#pragma unroll
        for (int h = 0; h < 2; ++h)
#pragma unroll
            for (int n = 0; n < 2; ++n) acc[m][h][n] = (f32x4){0.f, 0.f, 0.f, 0.f};

    auto STAGE = [&](int slot) {
#pragma unroll
        for (int i = 0; i < 2; ++i) {
            GLOAD16(aSrc[i], ALp + slot * 8192 + i * 4096 + wid * 512);
            aSrc[i] += 64;
        }
        GLOAD16(bSrc, BLp + slot * 4096 + wid * 512);
        bSrc += 64;
    };

    STAGE(0);
    STAGE(1);

    int cSwz = ((lk ^ ((lr >> 1) & 3)) << 3);
    int cur = 0, stg = 2;

#pragma unroll 1
    for (int kt = 0; kt < 32; ++kt) {
        if (kt == 31) asm volatile("s_waitcnt vmcnt(0)" ::: "memory");
        else          asm volatile("s_waitcnt vmcnt(3)" ::: "memory");
        __builtin_amdgcn_s_barrier();
        if (kt + 2 < 32) STAGE(stg);

        const unsigned short* Ab = ALp + cur * 8192 + cSwz;
        const unsigned short* Bb = BLp + cur * 4096 + cSwz;
        bf16x8 af[4], bfr[2][2];
#pragma unroll
        for (int m = 0; m < 4; ++m)
            af[m] = *(const bf16x8*)(Ab + (wm * 64 + m * 16 + lr) * 32);
#pragma unroll
        for (int h = 0; h < 2; ++h)
#pragma unroll
            for (int n = 0; n < 2; ++n)
                bfr[h][n] = *(const bf16x8*)(Bb + (h * 64 + wn * 32 + n * 16 + lr) * 32);
        __builtin_amdgcn_s_setprio(1);
#pragma unroll
        for (int h = 0; h < 2; ++h)
#pragma unroll
            for (int m = 0; m < 4; ++m)
#pragma unroll
                for (int n = 0; n < 2; ++n)
                    acc[m][h][n] = __builtin_amdgcn_mfma_f32_16x16x32_bf16(
                        af[m], bfr[h][n], acc[m][h][n], 0, 0, 0);
        __builtin_amdgcn_s_setprio(0);

        cur = cur + 1; if (cur == 3) cur = 0;
        stg = stg + 1; if (stg == 3) stg = 0;
    }

#pragma unroll
    for (int m = 0; m < 4; ++m)
#pragma unroll
        for (int n = 0; n < 2; ++n)
#pragma unroll
            for (int q = 0; q < 4; ++q) {
                int rl = wm * 64 + m * 16 + lk * 4 + q;
                if (r0 + rl < n_e) {
                    float v1 = acc[m][0][n][q];
                    float v2 = acc[m][1][n][q];
                    float hv = v1 * (1.0f / (1.0f + __expf(-v1))) * v2;
                    hbuf[(size_t)(p0 + rl) * HPAD + (j0 + wn * 32 + n * 16 + lr)] = f2bf(hv);
                }
            }
}

// ---------------- GEMM2 + gated scatter-add: out[tok] += w * (h @ W3) -------
// BM=256 x BN=256 d, BK=32, 1024 thr, 16 waves (4M x 4N), dbuf 64KB.
__global__ __launch_bounds__(1024, 2) void k_gemm2(
    const unsigned short* __restrict__ hbuf,
    const unsigned short* __restrict__ w3t,
    const int* __restrict__ ctrl,
    const int* __restrict__ ptok,
    const float* __restrict__ pw,
    float* __restrict__ out) {
    int e = blockIdx.z;
    int n_e = ctrl[e];
    int r0 = blockIdx.y * 256;
    if (r0 >= n_e) return;
    int p0 = ctrl[16 + e] + r0;
    int d0 = blockIdx.x * 256;

    __shared__ unsigned short AL[2][256][32];   // 32 KB
    __shared__ unsigned short BL[2][256][32];   // 32 KB

    int tid = threadIdx.x, lane = tid & 63, wid = tid >> 6;   // wid 0..15
    int wm = wid >> 2, wn = wid & 3;            // 4M x 4N, per-wave 64x64
    int lr = lane & 15, lk = lane >> 4;

    unsigned short* ALp = &AL[0][0][0];
    unsigned short* BLp = &BL[0][0][0];

    int swzB = (((tid & 3) ^ ((tid >> 3) & 3)) << 4);
    const char* aSrc;
    {
        int row = tid >> 2;                     // 0..255
        int arr = (r0 + row < n_e) ? row : 0;
        aSrc = (const char*)(hbuf + (size_t)(p0 + arr) * HPAD) + swzB;
    }
    const char* bSrc = (const char*)(w3t + ((size_t)e * 1024 + d0 + (tid >> 2)) * HPAD) + swzB;

    f32x4 acc[4][4];
#pragma unroll
    for (int m = 0; m < 4; ++m)
#pragma unroll
        for (int n = 0; n < 4; ++n) acc[m][n] = (f32x4){0.f, 0.f, 0.f, 0.f};

    auto STAGE = [&](int slot) {
        GLOAD16(aSrc, ALp + slot * 8192 + wid * 512);
        aSrc += 64;
        GLOAD16(bSrc, BLp + slot * 8192 + wid * 512);
        bSrc += 64;
    };

    STAGE(0);
    STAGE(1);

    int cSwz = ((lk ^ ((lr >> 1) & 3)) << 3);

#pragma unroll 1
    for (int kt = 0; kt < 86; ++kt) {
        int cur = kt & 1;
        if (kt == 85) asm volatile("s_waitcnt vmcnt(0)" ::: "memory");
        else          asm volatile("s_waitcnt vmcnt(2)" ::: "memory");
        __builtin_amdgcn_s_barrier();

        const unsigned short* Ab = ALp + cur * 8192 + cSwz;
        const unsigned short* Bb = BLp + cur * 8192 + cSwz;
        bf16x8 af[4], bfr[4];
#pragma unroll
        for (int m = 0; m < 4; ++m)
            af[m] = *(const bf16x8*)(Ab + (wm * 64 + m * 16 + lr) * 32);
#pragma unroll
        for (int n = 0; n < 4; ++n)
            bfr[n] = *(const bf16x8*)(Bb + (wn * 64 + n * 16 + lr) * 32);
        __builtin_amdgcn_s_setprio(1);
#pragma unroll
        for (int m = 0; m < 4; ++m)
#pragma unroll
            for (int n = 0; n < 4; ++n)
                acc[m][n] = __builtin_amdgcn_mfma_f32_16x16x32_bf16(
                    af[m], bfr[n], acc[m][n], 0, 0, 0);
        __builtin_amdgcn_s_setprio(0);

        asm volatile("s_waitcnt lgkmcnt(0)" ::: "memory");
        __builtin_amdgcn_sched_barrier(0);
        __builtin_amdgcn_s_barrier();
        if (kt + 2 < 86) STAGE(cur);
    }

#pragma unroll
    for (int m = 0; m < 4; ++m) {
        int rl0 = wm * 64 + m * 16 + lk * 4;
#pragma unroll
        for (int q = 0; q < 4; ++q) {
            int rl = rl0 + q;
            if (r0 + rl < n_e) {
                int pp = p0 + rl;
                int tok = ptok[pp];
                float w = pw[pp];
                float* orow = out + (size_t)tok * DIMD + d0;
#pragma unroll
                for (int n = 0; n < 4; ++n) {
                    atomicAdd(orow + (wn * 64 + n * 16 + lr), w * acc[m][n][q]);
                }
            }
        }
    }
}

extern "C" void kernel_launch(void* const* d_in, const int* in_sizes, int n_in,
                              void* d_out, int out_size, void* d_ws, size_t ws_size,
                              hipStream_t stream) {
    const float* x   = (const float*)d_in[0];
    const float* wr  = (const float*)d_in[1];
    const float* w12 = (const float*)d_in[2];
    const float* w3  = (const float*)d_in[3];
    float* out = (float*)d_out;

    char* ws = (char*)d_ws;
    int*            ctrl = (int*)(ws + WS_CTRL);
    int*            topi = (int*)(ws + WS_TOPI);
    float*          topw = (float*)(ws + WS_TOPW);
    float*          pw   = (float*)(ws + WS_PW);
    int*            ptok = (int*)(ws + WS_PTOK);
    unsigned short* xb   = (unsigned short*)(ws + WS_XB);
    unsigned short* w12t = (unsigned short*)(ws + WS_W12T);
    unsigned short* w3t  = (unsigned short*)(ws + WS_W3T);
    unsigned short* hbuf = (unsigned short*)(ws + WS_HBUF);

    (void)ws_size; (void)in_sizes; (void)n_in; (void)out_size;

    (void)hipMemsetAsync(ctrl, 0, 256, stream);
    (void)hipMemsetAsync(out, 0, (size_t)T_TOK * DIMD * sizeof(float), stream);
    k_router<<<2048, 256, 0, stream>>>((const float4*)x, wr, (ushort4*)xb, topi, topw, ctrl);
    k_cvt_w12t<<<dim3(172, 8, 8), 256, 0, stream>>>(w12, w12t);
    k_cvt_w3t<<<dim3(22, 32, 8), 256, 0, stream>>>(w3, w3t);
    k_scan<<<1, 64, 0, stream>>>(ctrl);
    k_compact<<<32, 256, 0, stream>>>(topi, topw, ctrl, ptok, pw);
    // gemm1 split over 4 dispatches (2 experts each) for profiler visibility
    k_gemm1<<<dim3(43, 32, 2), 512, 0, stream>>>(xb, w12t, ctrl, ptok, hbuf, 0);
    k_gemm1<<<dim3(43, 32, 2), 512, 0, stream>>>(xb, w12t, ctrl, ptok, hbuf, 2);
    k_gemm1<<<dim3(43, 32, 2), 512, 0, stream>>>(xb, w12t, ctrl, ptok, hbuf, 4);
    k_gemm1<<<dim3(43, 32, 2), 512, 0, stream>>>(xb, w12t, ctrl, ptok, hbuf, 6);
    k_gemm2<<<dim3(4, 32, 8), 1024, 0, stream>>>(hbuf, w3t, ctrl, ptok, pw, out);
}

// Round 13
// 596.088 us; speedup vs baseline: 1.5302x; 1.5302x over previous
//
#include <hip/hip_runtime.h>

// ---------------------------------------------------------------------------
// MoE forward (top-2 of 8 experts), sparse-routed, bf16 MFMA.
// Round 13: consolidation.
//  - gemm1: merged single dispatch (R10 engine, 719 TF, 0 conflicts).
//  - gemm2: R10 tri-buffer engine (512 active blocks = 2/CU) with PLAIN
//    coalesced pout stores (atomic-tail removed); k_combine rebuilds out.
//  - dispatch count 11 -> 6: router loses ctrl atomics; k_pack (1 block,
//    LDS scan, deterministic) replaces memset+scan+compact; both weight
//    conversions merged into one flat-grid kernel; memset(out) dropped.
// ---------------------------------------------------------------------------

typedef __bf16 bf16x8 __attribute__((ext_vector_type(8)));
typedef float f32x4 __attribute__((ext_vector_type(4)));
typedef unsigned short us8 __attribute__((ext_vector_type(8)));

#define T_TOK 8192
#define DIMD 1024
#define NEXP 8
#define HID 2730
#define HPAD 2752
#define H2PAD 5504
#define NPAIR 16384

#define WS_CTRL  ((size_t)0)
#define WS_TOPI  ((size_t)256)
#define WS_TOPW  (WS_TOPI + 65536)
#define WS_POS   (WS_TOPW + 65536)
#define WS_PTOK  (WS_POS + 65536)
#define WS_XB    (WS_PTOK + 65536)
#define WS_W12T  (WS_XB + (size_t)16777216)
#define WS_W3T   (WS_W12T + (size_t)90177536)
#define WS_HBUF  (WS_W3T + (size_t)45088768)
#define WS_POUT  (WS_HBUF + (size_t)90177536)

#define GLOAD16(g, l) __builtin_amdgcn_global_load_lds( \
    (const __attribute__((address_space(1))) void*)(g), \
    (__attribute__((address_space(3))) void*)(l), 16, 0, 0)

__device__ __forceinline__ unsigned short f2bf(float f) {
    unsigned int u = __float_as_uint(f);
    u += 0x7fffu + ((u >> 16) & 1u);
    return (unsigned short)(u >> 16);
}

// ---------------- merged weight conversion (flat grid) ----------------------
// blocks [0, 11008):  W12 -> w12t [e][half][jp 2752][k 1024]
// blocks [11008, 16640): W3 -> w3t [e][d 1024][k 2752]
__global__ void k_cvt_all(const float* __restrict__ w12, const float* __restrict__ w3,
                          unsigned short* __restrict__ w12t, unsigned short* __restrict__ w3t) {
    int bid = blockIdx.x;
    int t = threadIdx.x;
    __shared__ float tile[32][133];
    if (bid < 11008) {
        int jt = bid % 172, kt = (bid / 172) & 7, e = bid / 1376;
        int half = jt / 86, jt2 = jt % 86;
        int jh0 = jt2 * 32, k0 = kt * 128;
        {
            int lane_j = t & 15, krow = t >> 4;
#pragma unroll
            for (int p = 0; p < 8; ++p) {
                int kk = p * 16 + krow;
                int j = jh0 + lane_j * 2;
                float2 v = make_float2(0.f, 0.f);
                if (j < HID)
                    v = *(const float2*)(w12 + (size_t)(e * 1024 + k0 + kk) * 5460 + half * HID + j);
                tile[lane_j * 2][kk] = v.x;
                tile[lane_j * 2 + 1][kk] = v.y;
            }
        }
        __syncthreads();
        {
            int jj = t >> 3, kc = t & 7;
            unsigned short* dst = w12t + ((size_t)e * H2PAD + half * HPAD + jh0 + jj) * 1024 + k0;
#pragma unroll
            for (int cc = 0; cc < 2; ++cc) {
                int c = kc + cc * 8;
                us8 v;
#pragma unroll
                for (int b = 0; b < 8; ++b) v[b] = f2bf(tile[jj][c * 8 + b]);
                *(us8*)(dst + c * 8) = v;
            }
        }
    } else {
        int b2 = bid - 11008;
        int kt = b2 % 22, dt = (b2 / 22) & 31, e = b2 / 704;
        int k0 = kt * 128, d0 = dt * 32;
        {
            int lane_d = t & 15, krow = t >> 4;
#pragma unroll
            for (int p = 0; p < 8; ++p) {
                int kk = k0 + p * 16 + krow;
                float2 v = make_float2(0.f, 0.f);
                if (kk < HID)
                    v = *(const float2*)(w3 + (size_t)(e * HID + kk) * 1024 + d0 + lane_d * 2);
                tile[lane_d * 2][p * 16 + krow] = v.x;
                tile[lane_d * 2 + 1][p * 16 + krow] = v.y;
            }
        }
        __syncthreads();
        {
            int dd = t >> 3, kc = t & 7;
            unsigned short* dst = w3t + ((size_t)e * 1024 + d0 + dd) * HPAD + k0;
#pragma unroll
            for (int cc = 0; cc < 2; ++cc) {
                int c = kc + cc * 8;
                if (k0 + c * 8 < HPAD) {
                    us8 v;
#pragma unroll
                    for (int b = 0; b < 8; ++b) v[b] = f2bf(tile[dd][c * 8 + b]);
                    *(us8*)(dst + c * 8) = v;
                }
            }
        }
    }
}

// ---------------- router (fused x->bf16): fp64 logits, stable top-2 ---------
__global__ void k_router(const float4* __restrict__ x4, const float* __restrict__ wr,
                         ushort4* __restrict__ xb4,
                         int* __restrict__ topi, float* __restrict__ topw) {
    int wid = threadIdx.x >> 6, lane = threadIdx.x & 63;
    int t = blockIdx.x * 4 + wid;
    const float4* xr = x4 + (size_t)t * 256;
    double acc[NEXP];
#pragma unroll
    for (int e = 0; e < NEXP; ++e) acc[e] = 0.0;
#pragma unroll
    for (int it = 0; it < 4; ++it) {
        int d4 = it * 64 + lane;
        float4 v = xr[d4];
        ushort4 r;
        r.x = f2bf(v.x); r.y = f2bf(v.y); r.z = f2bf(v.z); r.w = f2bf(v.w);
        xb4[(size_t)t * 256 + d4] = r;
        const float* w = wr + (size_t)d4 * 4 * NEXP;
#pragma unroll
        for (int e = 0; e < NEXP; ++e) {
            acc[e] += (double)v.x * (double)w[e]
                    + (double)v.y * (double)w[NEXP + e]
                    + (double)v.z * (double)w[2 * NEXP + e]
                    + (double)v.w * (double)w[3 * NEXP + e];
        }
    }
#pragma unroll
    for (int e = 0; e < NEXP; ++e) {
        for (int off = 32; off > 0; off >>= 1) acc[e] += __shfl_down(acc[e], off);
    }
    if (lane == 0) {
        double b0 = -1e300, b1 = -1e300; int i0 = 0, i1 = 0;
#pragma unroll
        for (int e = 0; e < NEXP; ++e) {
            double v = acc[e];
            if (v > b0) { b1 = b0; i1 = i0; b0 = v; i0 = e; }
            else if (v > b1) { b1 = v; i1 = e; }
        }
        float e1 = expf((float)(b1 - b0));
        float w0 = 1.0f / (1.0f + e1);
        float w1 = e1 / (1.0f + e1);
        topi[2 * t] = i0; topi[2 * t + 1] = i1;
        topw[2 * t] = w0; topw[2 * t + 1] = w1;
    }
}

// ---------------- pack: counts + scan + stable compact, one block -----------
// Deterministic: positions ordered by (token, k). Writes ctrl[e]=cnt,
// ctrl[16+e]=offset, ptok[p]=token, pos[2t+k]=p.
__global__ __launch_bounds__(1024) void k_pack(const int* __restrict__ topi,
                                               int* __restrict__ ctrl,
                                               int* __restrict__ ptok,
                                               int* __restrict__ pos) {
    __shared__ int scnt[NEXP][1024];
    __shared__ int offs[NEXP];
    int tid = threadIdx.x;
    int lc[NEXP];
#pragma unroll
    for (int e = 0; e < NEXP; ++e) lc[e] = 0;
    int t0 = tid * 8;                      // 8 tokens per thread
#pragma unroll
    for (int i = 0; i < 8; ++i) {
        int t = t0 + i;
        lc[topi[2 * t]]++;
        lc[topi[2 * t + 1]]++;
    }
#pragma unroll
    for (int e = 0; e < NEXP; ++e) scnt[e][tid] = lc[e];
    __syncthreads();
    // Hillis-Steele inclusive scan over 1024 threads, all experts per step
    for (int off = 1; off < 1024; off <<= 1) {
        int v[NEXP];
#pragma unroll
        for (int e = 0; e < NEXP; ++e) v[e] = (tid >= off) ? scnt[e][tid - off] : 0;
        __syncthreads();
#pragma unroll
        for (int e = 0; e < NEXP; ++e) scnt[e][tid] += v[e];
        __syncthreads();
    }
    if (tid == 0) {
        int s = 0;
#pragma unroll
        for (int e = 0; e < NEXP; ++e) {
            int c = scnt[e][1023];
            ctrl[e] = c;
            ctrl[16 + e] = s;
            offs[e] = s;
            s += c;
        }
        ctrl[16 + NEXP] = s;
    }
    __syncthreads();
    int r[NEXP];
#pragma unroll
    for (int e = 0; e < NEXP; ++e) r[e] = offs[e] + scnt[e][tid] - lc[e];  // exclusive base
#pragma unroll
    for (int i = 0; i < 8; ++i) {
        int t = t0 + i;
#pragma unroll
        for (int k = 0; k < 2; ++k) {
            int e = topi[2 * t + k];
            int p = r[e]++;
            ptok[p] = t;
            pos[2 * t + k] = p;
        }
    }
}

// ---------------- GEMM1 + GLU: h = silu(x@W1)*(x@W2), bf16 out --------------
// BM=256 x BN=128(64j x 2 halves), BK=32, 512 thr, 8 waves (4M x 2N).
// Tri-buffered LDS 72KB (2 blocks/CU), 1 barrier/K-step, vmcnt(3).
__global__ __launch_bounds__(512, 4) void k_gemm1(
    const unsigned short* __restrict__ xb,
    const unsigned short* __restrict__ w12t,
    const int* __restrict__ ctrl,
    const int* __restrict__ ptok,
    unsigned short* __restrict__ hbuf) {
    int e = blockIdx.z;
    int n_e = ctrl[e];
    int r0 = blockIdx.y * 256;
    if (r0 >= n_e) return;
    int p0 = ctrl[16 + e] + r0;
    int j0 = blockIdx.x * 64;

    __shared__ unsigned short AL[3][256][32];   // 48 KB
    __shared__ unsigned short BL[3][128][32];   // 24 KB

    int tid = threadIdx.x, lane = tid & 63, wid = tid >> 6;
    int wm = wid >> 1, wn = wid & 1;            // 4M x 2N
    int lr = lane & 15, lk = lane >> 4;

    unsigned short* ALp = &AL[0][0][0];
    unsigned short* BLp = &BL[0][0][0];

    int swzB = (((tid & 3) ^ ((tid >> 3) & 3)) << 4);
    const char* aSrc[2];
#pragma unroll
    for (int i = 0; i < 2; ++i) {
        int row = i * 128 + (tid >> 2);
        int tok = (r0 + row < n_e) ? ptok[p0 + row] : ptok[p0];
        aSrc[i] = (const char*)(xb + (size_t)tok * 1024) + swzB;
    }
    const char* bSrc;
    {
        int r = tid >> 2;                       // 0..127: half*64 + jj
        int half = r >> 6, jj = r & 63;
        bSrc = (const char*)(w12t + ((size_t)e * H2PAD + half * HPAD + j0 + jj) * 1024) + swzB;
    }

    f32x4 acc[4][2][2];
#pragma unroll
    for (int m = 0; m < 4; ++m)
#pragma unroll
        for (int h = 0; h < 2; ++h)
#pragma unroll
            for (int n = 0; n < 2; ++n) acc[m][h][n] = (f32x4){0.f, 0.f, 0.f, 0.f};

    auto STAGE = [&](int slot) {
#pragma unroll
        for (int i = 0; i < 2; ++i) {
            GLOAD16(aSrc[i], ALp + slot * 8192 + i * 4096 + wid * 512);
            aSrc[i] += 64;
        }
        GLOAD16(bSrc, BLp + slot * 4096 + wid * 512);
        bSrc += 64;
    };

    STAGE(0);
    STAGE(1);

    int cSwz = ((lk ^ ((lr >> 1) & 3)) << 3);
    int cur = 0, stg = 2;

#pragma unroll 1
    for (int kt = 0; kt < 32; ++kt) {
        if (kt == 31) asm volatile("s_waitcnt vmcnt(0)" ::: "memory");
        else          asm volatile("s_waitcnt vmcnt(3)" ::: "memory");
        __builtin_amdgcn_s_barrier();
        if (kt + 2 < 32) STAGE(stg);

        const unsigned short* Ab = ALp + cur * 8192 + cSwz;
        const unsigned short* Bb = BLp + cur * 4096 + cSwz;
        bf16x8 af[4], bfr[2][2];
#pragma unroll
        for (int m = 0; m < 4; ++m)
            af[m] = *(const bf16x8*)(Ab + (wm * 64 + m * 16 + lr) * 32);
#pragma unroll
        for (int h = 0; h < 2; ++h)
#pragma unroll
            for (int n = 0; n < 2; ++n)
                bfr[h][n] = *(const bf16x8*)(Bb + (h * 64 + wn * 32 + n * 16 + lr) * 32);
        __builtin_amdgcn_s_setprio(1);
#pragma unroll
        for (int h = 0; h < 2; ++h)
#pragma unroll
            for (int m = 0; m < 4; ++m)
#pragma unroll
                for (int n = 0; n < 2; ++n)
                    acc[m][h][n] = __builtin_amdgcn_mfma_f32_16x16x32_bf16(
                        af[m], bfr[h][n], acc[m][h][n], 0, 0, 0);
        __builtin_amdgcn_s_setprio(0);

        cur = cur + 1; if (cur == 3) cur = 0;
        stg = stg + 1; if (stg == 3) stg = 0;
    }

#pragma unroll
    for (int m = 0; m < 4; ++m)
#pragma unroll
        for (int n = 0; n < 2; ++n)
#pragma unroll
            for (int q = 0; q < 4; ++q) {
                int rl = wm * 64 + m * 16 + lk * 4 + q;
                if (r0 + rl < n_e) {
                    float v1 = acc[m][0][n][q];
                    float v2 = acc[m][1][n][q];
                    float hv = v1 * (1.0f / (1.0f + __expf(-v1))) * v2;
                    hbuf[(size_t)(p0 + rl) * HPAD + (j0 + wn * 32 + n * 16 + lr)] = f2bf(hv);
                }
            }
}

// ---------------- GEMM2: pout[p] = h[p] @ W3  (plain coalesced stores) ------
// BM=256 x BN=128 d, BK=32, 512 thr, 8 waves (4M x 2N), NT=86, tri-buffer.
__global__ __launch_bounds__(512, 4) void k_gemm2(
    const unsigned short* __restrict__ hbuf,
    const unsigned short* __restrict__ w3t,
    const int* __restrict__ ctrl,
    float* __restrict__ pout) {
    int e = blockIdx.z;
    int n_e = ctrl[e];
    int r0 = blockIdx.y * 256;
    if (r0 >= n_e) return;
    int p0 = ctrl[16 + e] + r0;
    int d0 = blockIdx.x * 128;

    __shared__ unsigned short AL[3][256][32];
    __shared__ unsigned short BL[3][128][32];

    int tid = threadIdx.x, lane = tid & 63, wid = tid >> 6;
    int wm = wid >> 1, wn = wid & 1;
    int lr = lane & 15, lk = lane >> 4;

    unsigned short* ALp = &AL[0][0][0];
    unsigned short* BLp = &BL[0][0][0];

    int swzB = (((tid & 3) ^ ((tid >> 3) & 3)) << 4);
    const char* aSrc[2];
#pragma unroll
    for (int i = 0; i < 2; ++i) {
        int row = i * 128 + (tid >> 2);
        int arr = (r0 + row < n_e) ? row : 0;
        aSrc[i] = (const char*)(hbuf + (size_t)(p0 + arr) * HPAD) + swzB;
    }
    const char* bSrc = (const char*)(w3t + ((size_t)e * 1024 + d0 + (tid >> 2)) * HPAD) + swzB;

    f32x4 acc[4][4];
#pragma unroll
    for (int m = 0; m < 4; ++m)
#pragma unroll
        for (int n = 0; n < 4; ++n) acc[m][n] = (f32x4){0.f, 0.f, 0.f, 0.f};

    auto STAGE = [&](int slot) {
#pragma unroll
        for (int i = 0; i < 2; ++i) {
            GLOAD16(aSrc[i], ALp + slot * 8192 + i * 4096 + wid * 512);
            aSrc[i] += 64;
        }
        GLOAD16(bSrc, BLp + slot * 4096 + wid * 512);
        bSrc += 64;
    };

    STAGE(0);
    STAGE(1);

    int cSwz = ((lk ^ ((lr >> 1) & 3)) << 3);
    int cur = 0, stg = 2;

#pragma unroll 1
    for (int kt = 0; kt < 86; ++kt) {
        if (kt == 85) asm volatile("s_waitcnt vmcnt(0)" ::: "memory");
        else          asm volatile("s_waitcnt vmcnt(3)" ::: "memory");
        __builtin_amdgcn_s_barrier();
        if (kt + 2 < 86) STAGE(stg);

        const unsigned short* Ab = ALp + cur * 8192 + cSwz;
        const unsigned short* Bb = BLp + cur * 4096 + cSwz;
        bf16x8 af[4], bfr[4];
#pragma unroll
        for (int m = 0; m < 4; ++m)
            af[m] = *(const bf16x8*)(Ab + (wm * 64 + m * 16 + lr) * 32);
#pragma unroll
        for (int n = 0; n < 4; ++n)
            bfr[n] = *(const bf16x8*)(Bb + (wn * 64 + n * 16 + lr) * 32);
        __builtin_amdgcn_s_setprio(1);
#pragma unroll
        for (int m = 0; m < 4; ++m)
#pragma unroll
            for (int n = 0; n < 4; ++n)
                acc[m][n] = __builtin_amdgcn_mfma_f32_16x16x32_bf16(
                    af[m], bfr[n], acc[m][n], 0, 0, 0);
        __builtin_amdgcn_s_setprio(0);

        cur = cur + 1; if (cur == 3) cur = 0;
        stg = stg + 1; if (stg == 3) stg = 0;
    }

#pragma unroll
    for (int m = 0; m < 4; ++m) {
        int rl0 = wm * 64 + m * 16 + lk * 4;
#pragma unroll
        for (int q = 0; q < 4; ++q) {
            int rl = rl0 + q;
            if (r0 + rl < n_e) {
                float* orow = pout + (size_t)(p0 + rl) * DIMD + d0;
#pragma unroll
                for (int n = 0; n < 4; ++n) {
                    orow[wn * 64 + n * 16 + lr] = acc[m][n][q];
                }
            }
        }
    }
}

// ---------------- combine: out[t] = w0*pout[pos0] + w1*pout[pos1] -----------
__global__ void k_combine(const float4* __restrict__ pout, const int* __restrict__ pos,
                          const float* __restrict__ topw, float4* __restrict__ out) {
    int idx = blockIdx.x * 256 + threadIdx.x;
    int tok = idx >> 8, c = idx & 255;
    int p0 = pos[2 * tok], p1 = pos[2 * tok + 1];
    float w0 = topw[2 * tok], w1 = topw[2 * tok + 1];
    float4 a = pout[(size_t)p0 * 256 + c];
    float4 b = pout[(size_t)p1 * 256 + c];
    float4 r;
    r.x = w0 * a.x + w1 * b.x;
    r.y = w0 * a.y + w1 * b.y;
    r.z = w0 * a.z + w1 * b.z;
    r.w = w0 * a.w + w1 * b.w;
    out[idx] = r;
}

extern "C" void kernel_launch(void* const* d_in, const int* in_sizes, int n_in,
                              void* d_out, int out_size, void* d_ws, size_t ws_size,
                              hipStream_t stream) {
    const float* x   = (const float*)d_in[0];
    const float* wr  = (const float*)d_in[1];
    const float* w12 = (const float*)d_in[2];
    const float* w3  = (const float*)d_in[3];
    float* out = (float*)d_out;

    char* ws = (char*)d_ws;
    int*            ctrl = (int*)(ws + WS_CTRL);
    int*            topi = (int*)(ws + WS_TOPI);
    float*          topw = (float*)(ws + WS_TOPW);
    int*            pos  = (int*)(ws + WS_POS);
    int*            ptok = (int*)(ws + WS_PTOK);
    unsigned short* xb   = (unsigned short*)(ws + WS_XB);
    unsigned short* w12t = (unsigned short*)(ws + WS_W12T);
    unsigned short* w3t  = (unsigned short*)(ws + WS_W3T);
    unsigned short* hbuf = (unsigned short*)(ws + WS_HBUF);
    float*          pout = (float*)(ws + WS_POUT);

    (void)ws_size; (void)in_sizes; (void)n_in; (void)out_size;

    k_router<<<2048, 256, 0, stream>>>((const float4*)x, wr, (ushort4*)xb, topi, topw);
    k_cvt_all<<<16640, 256, 0, stream>>>(w12, w3, w12t, w3t);
    k_pack<<<1, 1024, 0, stream>>>(topi, ctrl, ptok, pos);
    k_gemm1<<<dim3(43, 32, 8), 512, 0, stream>>>(xb, w12t, ctrl, ptok, hbuf);
    k_gemm2<<<dim3(8, 32, 8), 512, 0, stream>>>(hbuf, w3t, ctrl, pout);
    k_combine<<<8192, 256, 0, stream>>>((const float4*)pout, pos, topw, (float4*)out);
}